// Round 7
// baseline (151.801 us; speedup 1.0000x reference)
//
#include <hip/hip_runtime.h>

#define HW   112
#define PH   114            // padded plane dim
#define KK   576
#define ROWB (PH * 128)                    // bytes per padded NHWC row
#define PLANE_SH (8 * PH * PH * 64)        // shorts per power plane
#define PLANE_B  (PLANE_SH * 2)            // bytes per plane
#define WB_OFF_SH (3 * PLANE_SH)
#define S_OFF_SH  (WB_OFF_SH + 36864)
// ws_size needed: ~40 MB

typedef __attribute__((ext_vector_type(8))) short s16x8;
typedef __attribute__((ext_vector_type(4))) float f32x4;
typedef __attribute__((ext_vector_type(2))) float f32x2;

__device__ inline unsigned short f2bf(float f) {
    unsigned u = __float_as_uint(f);
    u += 0x7FFF + ((u >> 16) & 1);            // RNE
    return (unsigned short)(u >> 16);
}

// ---- pass 1 (fused): pow planes + border zeros + weight transpose + row sums ----
// (verbatim from the verified R0/R1 kernel)
// Wb flat index: (((tap*2 + cc)*4 + nt)*64 + lane)*8 + j
//   k = cc*32 + (lane>>4)*8 + j, n = nt*16 + (lane&15), value = W[n][k*9 + tap]
__global__ __launch_bounds__(256) void prep_pow(const float* __restrict__ img,
                                                const float* __restrict__ W,
                                                unsigned short* __restrict__ pw,
                                                unsigned short* __restrict__ wb,
                                                float* __restrict__ S) {
    __shared__ __align__(16) unsigned short sA[3 * 112 * 72];   // [p][x][c pad 72]
    const int bid = blockIdx.x, t = threadIdx.x;
    if (bid < 896) {                         // pow: 8b * 112y
        const int b = bid / 112, y = bid - b * 112;
        const int c = t & 63, xq0 = t >> 6;
        const float4* src = (const float4*)(img + (((size_t)(b * 64 + c) * HW + y) * HW));
        #pragma unroll
        for (int i = 0; i < 7; ++i) {
            const int xq = xq0 + i * 4;
            const float4 v = src[xq];
            const float vv[4] = {v.x, v.y, v.z, v.w};
            #pragma unroll
            for (int u = 0; u < 4; ++u) {
                const float v1 = vv[u], v2 = v1 * v1, v3 = v2 * v1;
                const int x = xq * 4 + u;
                sA[x * 72 + c]         = f2bf(v1);
                sA[8064 + x * 72 + c]  = f2bf(v2);
                sA[16128 + x * 72 + c] = f2bf(v3);
            }
        }
        __syncthreads();
        for (int i = 0; i < 11; ++i) {
            const int ch = t + i * 256;
            if (ch >= 2688) break;           // 3p * 112x * 8 c-octs
            const int p = ch / 896, r = ch - p * 896;
            const int x = r >> 3, c8 = r & 7;
            const s16x8 val = *(const s16x8*)&sA[p * 8064 + x * 72 + c8 * 8];
            *(s16x8*)&pw[(size_t)p * PLANE_SH + ((size_t)(b * PH + y + 1) * PH + (x + 1)) * 64 + c8 * 8] = val;
        }
    } else if (bid < 920) {                  // border zeros: 3p * 8b
        const int k = bid - 896;
        const int p = k >> 3, b = k & 7;
        unsigned short* base = pw + (size_t)p * PLANE_SH + (size_t)b * PH * PH * 64;
        const s16x8 z = {0, 0, 0, 0, 0, 0, 0, 0};
        for (int i = 0; i < 15; ++i) {
            const int e = t + i * 256;
            if (e >= 3616) break;            // 452 border px * 8 c-octs
            const int n = e >> 3, c8 = e & 7;
            int x, yy;
            if (n < 114)      { yy = 0;   x = n; }
            else if (n < 228) { yy = 113; x = n - 114; }
            else { const int m2 = n - 228; yy = 1 + (m2 >> 1); x = (m2 & 1) ? 113 : 0; }
            *(s16x8*)&base[(yy * PH + x) * 64 + c8 * 8] = z;
        }
    } else if (bid < 1064) {                 // weight transpose: 144 blocks
        const int i   = (bid - 920) * 256 + t;
        const int j   = i & 7;
        const int l   = (i >> 3) & 63;
        const int nt  = (i >> 9) & 3;
        const int cc  = (i >> 11) & 1;
        const int tap = i >> 12;
        const int c   = cc * 32 + ((l >> 4) << 3) + j;
        const int o   = nt * 16 + (l & 15);
        wb[i] = f2bf(W[o * KK + c * 9 + tap]);
    } else {                                 // row sums
        __shared__ float partial[256];
        const int o = t >> 2, part = t & 3;
        const float4* row = (const float4*)(W + o * KK) + part * 36;
        float s = 0.f;
        for (int k = 0; k < 36; ++k) { float4 v = row[k]; s += v.x + v.y + v.z + v.w; }
        partial[t] = s;
        __syncthreads();
        if (part == 0) S[o] = partial[t] + partial[t + 1] + partial[t + 2] + partial[t + 3];
    }
}

// ---- pass 2: register-direct conv. NO LDS, NO barriers. ----
// block = 256 thr (4 waves); wave wv owns output rows 2wv, 2wv+1 of an 8x16 tile
// and a 32-oc half (oc2 from blockIdx). A-fragments load straight from the padded
// NHWC pw planes (L3-resident, written by prep_pow this iteration) with
// global_load_dwordx4 at the exact fragment addresses the R1 kernel verified:
//   lane (m = lane&15, q = lane>>4): pw row = y0 + 2wv + r4, x = x0 + m + kx,
//   channel-octet = cc*4 + q  ->  byte addr = ((b*PH + row)*PH + x)*128 + cc*64 + q*16
// B-fragments load from L2-hot wb (1 KB coalesced wave-loads), held in registers
// per cc-half. 108 wave-loads + 216 MFMA per wave, fully compiler-pipelined via
// counted vmcnt -- the m233 "stage+barrier" structural overhead is gone by design.
__global__ __launch_bounds__(256, 2) void conv_reg(const unsigned short* __restrict__ pw,
                                                   const unsigned short* __restrict__ wb,
                                                   const float* __restrict__ S,
                                                   float* __restrict__ out) {
    const int t = threadIdx.x, wv = t >> 6, lane = t & 63;
    const int m = lane & 15, q = lane >> 4;

    const int bid = blockIdx.x;       // 1568: b = bid&7 (XCD pin); oc-half pairs adjacent
    const int b = bid & 7;
    const int rest = bid >> 3;        // 0..195
    const int oc2 = rest & 1;
    const int r = rest >> 1;          // 0..97 = 14 ty * 7 tx
    const int ty = r / 7, tx = r - ty * 7;
    const int y0 = ty * 8, x0 = tx * 16;

    f32x4 acc[3][2][2];               // [power][at][ntl]
    #pragma unroll
    for (int p = 0; p < 3; ++p)
        #pragma unroll
        for (int at = 0; at < 2; ++at)
            #pragma unroll
            for (int ntl = 0; ntl < 2; ++ntl)
                acc[p][at][ntl] = (f32x4){0.f, 0.f, 0.f, 0.f};

    const char* wbase  = (const char*)wb + oc2 * 2048 + lane * 16;
    // lane-fixed A base: row y0+2wv, px x0+m, octet q (cc/kx/p/r4 added per cluster)
    const char* abase0 = (const char*)pw
        + ((size_t)(b * PH + y0 + 2 * wv) * PH + (x0 + m)) * 128 + q * 16;

    s16x8 bfr[9][2];                  // current cc's B fragments in registers

    #pragma unroll
    for (int cc = 0; cc < 2; ++cc) {
        #pragma unroll
        for (int tap = 0; tap < 9; ++tap)
            #pragma unroll
            for (int ntl = 0; ntl < 2; ++ntl)
                bfr[tap][ntl] = *(const s16x8*)(wbase + (tap * 2 + cc) * 4096 + ntl * 1024);

        #pragma unroll
        for (int kx = 0; kx < 3; ++kx) {
            #pragma unroll
            for (int p = 0; p < 3; ++p) {
                const char* ab = abase0 + (size_t)p * PLANE_B + cc * 64 + kx * 128;
                s16x8 af[4];
                #pragma unroll
                for (int r4 = 0; r4 < 4; ++r4)
                    af[r4] = *(const s16x8*)(ab + r4 * ROWB);
                #pragma unroll
                for (int ky = 0; ky < 3; ++ky)
                    #pragma unroll
                    for (int at = 0; at < 2; ++at)
                        #pragma unroll
                        for (int ntl = 0; ntl < 2; ++ntl)
                            acc[p][at][ntl] = __builtin_amdgcn_mfma_f32_16x16x32_bf16(
                                af[at + ky], bfr[ky * 3 + kx][ntl], acc[p][at][ntl], 0, 0, 0);
            }
        }
    }

    // ---- epilogue: telescoped diffs, f32x2 packed; D: n = lane&15, px = q*4+reg ----
    #pragma unroll
    for (int ntl = 0; ntl < 2; ++ntl) {
        const int o = (oc2 * 2 + ntl) * 16 + (lane & 15);
        const float Sv = S[o];
        const float fS = -0.000287f / 75.f * Sv;
        const float cg1 = 0.8448f  + 0.001309f * Sv;
        const float D1  = 0.52992f - 0.003809f * Sv;
        const float D2  = 0.45312f + 0.001546f * Sv;
        const float D3  = 1.152f   - 0.006386f * Sv;
        const float D4  = 0.91392f - 0.00283f  * Sv;
        #pragma unroll
        for (int at = 0; at < 2; ++at) {
            float res[4];
            #pragma unroll
            for (int h = 0; h < 2; ++h) {
                const f32x2 u1 = {acc[0][at][ntl][2 * h], acc[0][at][ntl][2 * h + 1]};
                const f32x2 u2 = {acc[1][at][ntl][2 * h], acc[1][at][ntl][2 * h + 1]};
                const f32x2 u3 = {acc[2][at][ntl][2 * h], acc[2][at][ntl][2 * h + 1]};
                const f32x2 f  = fS   + 0.00354667f * u1 - 0.00146267f * u2;
                const f32x2 g1 = cg1  + 0.00619f    * u1 - 0.009f      * u2 + 0.001383f * u3;
                const f32x2 d1 = D1   - 0.00316f    * u1 + 0.00416f    * u2 + 0.016117f * u3;
                const f32x2 d2 = D2   - 0.00116f    * u1 + 0.006717f   * u2 - 0.00248f  * u3;
                const f32x2 d3 = D3   - 0.000753f   * u1 + 0.005643f   * u2 - 0.00602f  * u3;
                const f32x2 d4 = D4   - 0.000691f   * u1 + 0.00085f    * u2 - 0.00487f  * u3;
                f32x2 E;
                E.x = __expf(-10.f * f.x);
                E.y = __expf(-10.f * f.y);
                const f32x2 den1 = 1.f + E * 4.4816890703f;
                const f32x2 den2 = 1.f + E * 9.9741824548f;
                const f32x2 den3 = 1.f + E * 24.5325301971f;
                const f32x2 den4 = 1.f + E * 49.4024491055f;
                f32x2 o2 = g1;
                o2.x += __builtin_amdgcn_rcpf(den1.x) * d1.x + __builtin_amdgcn_rcpf(den2.x) * d2.x
                      + __builtin_amdgcn_rcpf(den3.x) * d3.x + __builtin_amdgcn_rcpf(den4.x) * d4.x;
                o2.y += __builtin_amdgcn_rcpf(den1.y) * d1.y + __builtin_amdgcn_rcpf(den2.y) * d2.y
                      + __builtin_amdgcn_rcpf(den3.y) * d3.y + __builtin_amdgcn_rcpf(den4.y) * d4.y;
                res[2 * h] = o2.x; res[2 * h + 1] = o2.y;
            }
            const int y = y0 + 2 * wv + at;
            float* op = out + (((size_t)(b * 64 + o)) * HW + y) * HW + x0 + q * 4;
            *(float4*)op = make_float4(res[0], res[1], res[2], res[3]);
        }
    }
}

extern "C" void kernel_launch(void* const* d_in, const int* in_sizes, int n_in,
                              void* d_out, int out_size, void* d_ws, size_t ws_size,
                              hipStream_t stream) {
    const float* img = (const float*)d_in[0];
    const float* w   = (const float*)d_in[1];
    float* outp = (float*)d_out;
    unsigned short* pw = (unsigned short*)d_ws;
    unsigned short* wb = pw + WB_OFF_SH;
    float* S = (float*)(pw + S_OFF_SH);

    hipLaunchKernelGGL(prep_pow, dim3(1065), dim3(256), 0, stream, img, w, pw, wb, S);
    hipLaunchKernelGGL(conv_reg, dim3(1568), dim3(256), 0, stream, pw, wb, S, outp);
}

// Round 8
// 124.044 us; speedup vs baseline: 1.2238x; 1.2238x over previous
//
#include <hip/hip_runtime.h>

#define HW   112
#define PH   114            // padded plane dim
#define KK   576
#define ROWB (PH * 128)                    // bytes per padded NHWC row
#define PLANE_SH (8 * PH * PH * 64)        // shorts per power plane
#define PLANE_B  (PLANE_SH * 2)            // bytes per plane
#define WB_OFF_SH (3 * PLANE_SH)
#define S_OFF_SH  (WB_OFF_SH + 36864)

typedef __attribute__((ext_vector_type(8))) short s16x8;
typedef __attribute__((ext_vector_type(4))) float f32x4;
typedef __attribute__((ext_vector_type(2))) float f32x2;
typedef __attribute__((address_space(3))) unsigned int lds_u32;
typedef const __attribute__((address_space(1))) unsigned int glb_u32;

#define SWZ(px)  (((px) & 3) ^ (((px) >> 2) & 3))
#define LP_ROW   1152                      // 18 px * 64 B (linear -- gload_lds dest)
#define LP_PHASE 11520                     // 10 rows

__device__ inline unsigned short f2bf(float f) {
    unsigned u = __float_as_uint(f);
    u += 0x7FFF + ((u >> 16) & 1);            // RNE
    return (unsigned short)(u >> 16);
}

// ---- pass 1 (fused): pow planes + border zeros + weight transpose + row sums ----
// (verbatim from the verified R0/R1/R7 kernel)
__global__ __launch_bounds__(256) void prep_pow(const float* __restrict__ img,
                                                const float* __restrict__ W,
                                                unsigned short* __restrict__ pw,
                                                unsigned short* __restrict__ wb,
                                                float* __restrict__ S) {
    __shared__ __align__(16) unsigned short sA[3 * 112 * 72];   // [p][x][c pad 72]
    const int bid = blockIdx.x, t = threadIdx.x;
    if (bid < 896) {                         // pow: 8b * 112y
        const int b = bid / 112, y = bid - b * 112;
        const int c = t & 63, xq0 = t >> 6;
        const float4* src = (const float4*)(img + (((size_t)(b * 64 + c) * HW + y) * HW));
        #pragma unroll
        for (int i = 0; i < 7; ++i) {
            const int xq = xq0 + i * 4;
            const float4 v = src[xq];
            const float vv[4] = {v.x, v.y, v.z, v.w};
            #pragma unroll
            for (int u = 0; u < 4; ++u) {
                const float v1 = vv[u], v2 = v1 * v1, v3 = v2 * v1;
                const int x = xq * 4 + u;
                sA[x * 72 + c]         = f2bf(v1);
                sA[8064 + x * 72 + c]  = f2bf(v2);
                sA[16128 + x * 72 + c] = f2bf(v3);
            }
        }
        __syncthreads();
        for (int i = 0; i < 11; ++i) {
            const int ch = t + i * 256;
            if (ch >= 2688) break;           // 3p * 112x * 8 c-octs
            const int p = ch / 896, r = ch - p * 896;
            const int x = r >> 3, c8 = r & 7;
            const s16x8 val = *(const s16x8*)&sA[p * 8064 + x * 72 + c8 * 8];
            *(s16x8*)&pw[(size_t)p * PLANE_SH + ((size_t)(b * PH + y + 1) * PH + (x + 1)) * 64 + c8 * 8] = val;
        }
    } else if (bid < 920) {                  // border zeros: 3p * 8b
        const int k = bid - 896;
        const int p = k >> 3, b = k & 7;
        unsigned short* base = pw + (size_t)p * PLANE_SH + (size_t)b * PH * PH * 64;
        const s16x8 z = {0, 0, 0, 0, 0, 0, 0, 0};
        for (int i = 0; i < 15; ++i) {
            const int e = t + i * 256;
            if (e >= 3616) break;            // 452 border px * 8 c-octs
            const int n = e >> 3, c8 = e & 7;
            int x, yy;
            if (n < 114)      { yy = 0;   x = n; }
            else if (n < 228) { yy = 113; x = n - 114; }
            else { const int m2 = n - 228; yy = 1 + (m2 >> 1); x = (m2 & 1) ? 113 : 0; }
            *(s16x8*)&base[(yy * PH + x) * 64 + c8 * 8] = z;
        }
    } else if (bid < 1064) {                 // weight transpose: 144 blocks
        const int i   = (bid - 920) * 256 + t;
        const int j   = i & 7;
        const int l   = (i >> 3) & 63;
        const int nt  = (i >> 9) & 3;
        const int cc  = (i >> 11) & 1;
        const int tap = i >> 12;
        const int c   = cc * 32 + ((l >> 4) << 3) + j;
        const int o   = nt * 16 + (l & 15);
        wb[i] = f2bf(W[o * KK + c * 9 + tap]);
    } else {                                 // row sums
        __shared__ float partial[256];
        const int o = t >> 2, part = t & 3;
        const float4* row = (const float4*)(W + o * KK) + part * 36;
        float s = 0.f;
        for (int k = 0; k < 36; ++k) { float4 v = row[k]; s += v.x + v.y + v.z + v.w; }
        partial[t] = s;
        __syncthreads();
        if (part == 0) S[o] = partial[t] + partial[t + 1] + partial[t + 2] + partial[t + 3];
    }
}

// ---- pass 2: merged-oc conv, gload_lds-fed, 6-phase double-buffered ----
// 512 thr / 8 waves: wvr = wv&3 owns rows 2wvr,2wvr+1; oc2 = wv>>2 owns 32-oc half.
// One staged A phase (plane p, cc half: 11,520 B) serves BOTH oc halves -- staging
// traffic is half of R1's per-output, with zero VALU pack and zero ds_write
// (global_load_lds direct; pre-swizzled source, swizzled read -- R1's verified pair).
// Counted vmcnt(1): one phase (1-2 loads/wave) stays in flight across compute.
#define SB() __builtin_amdgcn_sched_barrier(0)

__global__ __launch_bounds__(512, 2) void conv_m2(const unsigned short* __restrict__ pw,
                                                  const unsigned short* __restrict__ wb,
                                                  const float* __restrict__ S,
                                                  float* __restrict__ out) {
    __shared__ __align__(16) char tile[2][LP_PHASE];   // 23,040 B

    const int t = threadIdx.x, wv = t >> 6, lane = t & 63;
    const int wvr = wv & 3, oc2 = wv >> 2;
    const int m = lane & 15, q = lane >> 4;

    const int bid = blockIdx.x;       // 784: b = bid&7 (XCD pin)
    const int b = bid & 7;
    const int r = bid >> 3;           // 0..97 = 14 ty * 7 tx
    const int ty = r / 7, tx = r - ty * 7;
    const int y0 = ty * 8, x0 = tx * 16;

    f32x4 acc[3][2][2];               // [power][at][ntl]
    #pragma unroll
    for (int p = 0; p < 3; ++p)
        #pragma unroll
        for (int at = 0; at < 2; ++at)
            #pragma unroll
            for (int ntl = 0; ntl < 2; ++ntl)
                acc[p][at][ntl] = (f32x4){0.f, 0.f, 0.f, 0.f};

    const char* pwin  = (const char*)pw + ((size_t)(b * PH + y0) * PH + x0) * 128;
    const char* wbase = (const char*)wb + oc2 * 2048 + lane * 16;
    s16x8 bfr[9][2];                  // current cc's B fragments in registers

    auto loadW = [&](int cc) {
        #pragma unroll
        for (int tap = 0; tap < 9; ++tap)
            #pragma unroll
            for (int ntl = 0; ntl < 2; ++ntl)
                bfr[tap][ntl] = *(const s16x8*)(wbase + (tap * 2 + cc) * 4096 + ntl * 1024);
    };

    // stage one (cc, plane) 11,520 B half-tile into buf; 720 x 16B gload_lds
    // (waves 0-3: 2 loads, waves 4-7: 1 -- vmcnt(1) is safe for both, see header)
    auto stage = [&](int cc, int p, int buf) {
        #pragma unroll
        for (int i = 0; i < 2; ++i) {
            const int f = i * 8192 + t * 16;
            if (f < LP_PHASE) {
                const int row = f / LP_ROW;
                const int r2  = f - row * LP_ROW;
                const int px  = r2 >> 6;
                const int c8s = (r2 >> 4) & 3;
                const int c8  = c8s ^ SWZ(px);
                const char* gp = pwin + (size_t)p * PLANE_B + row * ROWB + px * 128 + cc * 64 + c8 * 16;
                lds_u32* lp = (lds_u32*)(tile[buf] + i * 8192 + wv * 1024);
                __builtin_amdgcn_global_load_lds((glb_u32*)gp, lp, 16, 0, 0);
            }
        }
    };

    auto compute_plane = [&](const char* base, int p) {   // p compile-time at call sites
        #pragma unroll
        for (int kx = 0; kx < 3; ++kx) {
            const int pxr  = m + kx;
            const int c8sr = q ^ SWZ(pxr);
            const int abase = wvr * (2 * LP_ROW) + pxr * 64 + c8sr * 16;
            s16x8 af[4];
            #pragma unroll
            for (int r4 = 0; r4 < 4; ++r4)
                af[r4] = *(const s16x8*)&base[abase + r4 * LP_ROW];
            __builtin_amdgcn_s_setprio(1);
            #pragma unroll
            for (int ky = 0; ky < 3; ++ky)
                #pragma unroll
                for (int at = 0; at < 2; ++at)
                    #pragma unroll
                    for (int ntl = 0; ntl < 2; ++ntl)
                        acc[p][at][ntl] = __builtin_amdgcn_mfma_f32_16x16x32_bf16(
                            af[at + ky], bfr[ky * 3 + kx][ntl], acc[p][at][ntl], 0, 0, 0);
            __builtin_amdgcn_s_setprio(0);
        }
    };

#define VM(N)  asm volatile("s_waitcnt vmcnt(" #N ")" ::: "memory")
#define BAR()  __builtin_amdgcn_s_barrier()

    // prologue: W(cc0), then phases 0,1 into bufs 0,1
    loadW(0); SB();
    stage(0, 0, 0); stage(0, 1, 1); SB();

    // ph0: compute(cc0,p0,buf0); prefetch ph2 -> buf0
    VM(1); SB(); BAR(); SB();
    compute_plane(tile[0], 0);
    SB(); BAR(); SB(); stage(0, 2, 0); SB();
    // ph1: compute(cc0,p1,buf1); prefetch ph3 -> buf1
    VM(1); SB(); BAR(); SB();
    compute_plane(tile[1], 1);
    SB(); BAR(); SB(); stage(1, 0, 1); SB();
    // ph2: compute(cc0,p2,buf0); W(cc1); prefetch ph4 -> buf0
    VM(1); SB(); BAR(); SB();
    compute_plane(tile[0], 2);
    SB(); BAR(); SB(); loadW(1); SB(); stage(1, 1, 0); SB();
    // ph3: compute(cc1,p0,buf1); prefetch ph5 -> buf1
    VM(1); SB(); BAR(); SB();
    compute_plane(tile[1], 0);
    SB(); BAR(); SB(); stage(1, 2, 1); SB();
    // ph4: compute(cc1,p1,buf0)
    VM(1); SB(); BAR(); SB();
    compute_plane(tile[0], 1);
    SB(); BAR(); SB();
    // ph5: compute(cc1,p2,buf1) -- drain
    VM(0); SB(); BAR(); SB();
    compute_plane(tile[1], 2);

    // ---- epilogue: telescoped diffs, f32x2 packed; D: n = lane&15, px = q*4+reg ----
    #pragma unroll
    for (int ntl = 0; ntl < 2; ++ntl) {
        const int o = (oc2 * 2 + ntl) * 16 + (lane & 15);
        const float Sv = S[o];
        const float fS = -0.000287f / 75.f * Sv;
        const float cg1 = 0.8448f  + 0.001309f * Sv;
        const float D1  = 0.52992f - 0.003809f * Sv;
        const float D2  = 0.45312f + 0.001546f * Sv;
        const float D3  = 1.152f   - 0.006386f * Sv;
        const float D4  = 0.91392f - 0.00283f  * Sv;
        #pragma unroll
        for (int at = 0; at < 2; ++at) {
            float res[4];
            #pragma unroll
            for (int h = 0; h < 2; ++h) {
                const f32x2 u1 = {acc[0][at][ntl][2 * h], acc[0][at][ntl][2 * h + 1]};
                const f32x2 u2 = {acc[1][at][ntl][2 * h], acc[1][at][ntl][2 * h + 1]};
                const f32x2 u3 = {acc[2][at][ntl][2 * h], acc[2][at][ntl][2 * h + 1]};
                const f32x2 f  = fS   + 0.00354667f * u1 - 0.00146267f * u2;
                const f32x2 g1 = cg1  + 0.00619f    * u1 - 0.009f      * u2 + 0.001383f * u3;
                const f32x2 d1 = D1   - 0.00316f    * u1 + 0.00416f    * u2 + 0.016117f * u3;
                const f32x2 d2 = D2   - 0.00116f    * u1 + 0.006717f   * u2 - 0.00248f  * u3;
                const f32x2 d3 = D3   - 0.000753f   * u1 + 0.005643f   * u2 - 0.00602f  * u3;
                const f32x2 d4 = D4   - 0.000691f   * u1 + 0.00085f    * u2 - 0.00487f  * u3;
                f32x2 E;
                E.x = __expf(-10.f * f.x);
                E.y = __expf(-10.f * f.y);
                const f32x2 den1 = 1.f + E * 4.4816890703f;
                const f32x2 den2 = 1.f + E * 9.9741824548f;
                const f32x2 den3 = 1.f + E * 24.5325301971f;
                const f32x2 den4 = 1.f + E * 49.4024491055f;
                f32x2 o2 = g1;
                o2.x += __builtin_amdgcn_rcpf(den1.x) * d1.x + __builtin_amdgcn_rcpf(den2.x) * d2.x
                      + __builtin_amdgcn_rcpf(den3.x) * d3.x + __builtin_amdgcn_rcpf(den4.x) * d4.x;
                o2.y += __builtin_amdgcn_rcpf(den1.y) * d1.y + __builtin_amdgcn_rcpf(den2.y) * d2.y
                      + __builtin_amdgcn_rcpf(den3.y) * d3.y + __builtin_amdgcn_rcpf(den4.y) * d4.y;
                res[2 * h] = o2.x; res[2 * h + 1] = o2.y;
            }
            const int y = y0 + 2 * wvr + at;
            float* op = out + (((size_t)(b * 64 + o)) * HW + y) * HW + x0 + q * 4;
            *(float4*)op = make_float4(res[0], res[1], res[2], res[3]);
        }
    }
}

extern "C" void kernel_launch(void* const* d_in, const int* in_sizes, int n_in,
                              void* d_out, int out_size, void* d_ws, size_t ws_size,
                              hipStream_t stream) {
    const float* img = (const float*)d_in[0];
    const float* w   = (const float*)d_in[1];
    float* outp = (float*)d_out;
    unsigned short* pw = (unsigned short*)d_ws;
    unsigned short* wb = pw + WB_OFF_SH;
    float* S = (float*)(pw + S_OFF_SH);

    hipLaunchKernelGGL(prep_pow, dim3(1065), dim3(256), 0, stream, img, w, pw, wb, S);
    hipLaunchKernelGGL(conv_m2,  dim3(784),  dim3(512), 0, stream, pw, wb, S, outp);
}

// Round 9
// 108.992 us; speedup vs baseline: 1.3928x; 1.1381x over previous
//
#include <hip/hip_runtime.h>

#define HW   112
#define KK   576

typedef __attribute__((ext_vector_type(8))) short s16x8;
typedef __attribute__((ext_vector_type(4))) float f32x4;
typedef __attribute__((ext_vector_type(2))) float f32x2;

// LDS A-tile geometry: [cc 2][plane 3][row 10][px 18][granule 4 x 16B], row +32B pad
// so the stage ds_write pattern is 2-way (free) and reads spread banks.
#define LP_ROW   1184
#define LP_PHASE (10 * LP_ROW)            // 11,840 B per plane; 35,520 B per cc-half
#define SWZ(px)  (((px) & 3) ^ (((px) >> 2) & 3))

__device__ inline unsigned short f2bf(float f) {
    unsigned u = __float_as_uint(f);
    u += 0x7FFF + ((u >> 16) & 1);            // RNE
    return (unsigned short)(u >> 16);
}
// single-instruction packed f32->bf16 (RNE, bit-identical to f2bf on finite inputs)
__device__ inline unsigned pack2(float lo, float hi) {
    unsigned r;
    asm("v_cvt_pk_bf16_f32 %0, %1, %2" : "=v"(r) : "v"(lo), "v"(hi));
    return r;
}

// ---- tiny prep: weight transpose + row sums ----
// Wb flat index: (((tap*2 + cc)*4 + nt)*64 + lane)*8 + j
//   k = cc*32 + (lane>>4)*8 + j, n = nt*16 + (lane&15), value = W[n][k*9 + tap]
__global__ __launch_bounds__(256) void prep_w(const float* __restrict__ W,
                                              unsigned short* __restrict__ wb,
                                              float* __restrict__ S) {
    const int bid = blockIdx.x, t = threadIdx.x;
    if (bid < 144) {                         // weight transpose: 36,864 elements
        const int i   = bid * 256 + t;
        const int j   = i & 7;
        const int l   = (i >> 3) & 63;
        const int nt  = (i >> 9) & 3;
        const int cc  = (i >> 11) & 1;
        const int tap = i >> 12;
        const int c   = cc * 32 + ((l >> 4) << 3) + j;
        const int o   = nt * 16 + (l & 15);
        wb[i] = f2bf(W[o * KK + c * 9 + tap]);
    } else {                                 // row sums
        __shared__ float partial[256];
        const int o = t >> 2, part = t & 3;
        const float4* row = (const float4*)(W + o * KK) + part * 36;
        float s = 0.f;
        for (int k = 0; k < 36; ++k) { float4 v = row[k]; s += v.x + v.y + v.z + v.w; }
        partial[t] = s;
        __syncthreads();
        if (part == 0) S[o] = partial[t] + partial[t + 1] + partial[t + 2] + partial[t + 3];
    }
}

// ---- fused conv, merged oc halves: 512 thr / 8 waves per block ----
// Wave wv: wvr = wv&3 owns rows 2wvr,2wvr+1; oc2 = wv>>2 owns a 32-oc half.
// ONE stage (320 threads, units = (cc 2, cp 16, srow 10)) fills BOTH cc buffers in
// the prologue -- stage work, img loads, and ds_writes are done once per spatial
// tile instead of once per oc-half.
// Round-5 lesson: __launch_bounds__(512,4) clamped VGPR to 64 -> 81 MB of scratch
// spill (WRITE_SIZE 3.2x). (512,2) caps at 256; natural allocation ~80 stays
// <=128 so HW co-resides 2 blocks/CU (16 waves) -- the register-footprint TLP cap.
__global__ __launch_bounds__(512, 2) void conv_fused(const float* __restrict__ img,
                                                     const unsigned short* __restrict__ wb,
                                                     const float* __restrict__ S,
                                                     float* __restrict__ out) {
    __shared__ __align__(16) char tile[2][3 * LP_PHASE];   // 71,040 B -> 2 blocks/CU

    const int t = threadIdx.x, wv = t >> 6, lane = t & 63;
    const int wvr = wv & 3, oc2 = wv >> 2;
    const int m = lane & 15, q = lane >> 4;

    const int bid = blockIdx.x;       // 784: b = bid&7 (XCD pin)
    const int b = bid & 7;
    const int r = bid >> 3;           // 0..97 = 14 ty * 7 tx
    const int ty = r / 7, tx = r - ty * 7;
    const int y0 = ty * 8, x0 = tx * 16;

    f32x4 acc[3][2][2];               // [power][at][ntl]
    #pragma unroll
    for (int p = 0; p < 3; ++p)
        #pragma unroll
        for (int at = 0; at < 2; ++at)
            #pragma unroll
            for (int ntl = 0; ntl < 2; ++ntl)
                acc[p][at][ntl] = (f32x4){0.f, 0.f, 0.f, 0.f};

    const char* wbase = (const char*)wb + oc2 * 2048 + lane * 16;
    s16x8 bfr[9][2];                  // current cc's B fragments in registers

    auto loadW = [&](int cc) {
        #pragma unroll
        for (int tap = 0; tap < 9; ++tap)
            #pragma unroll
            for (int ntl = 0; ntl < 2; ++ntl)
                bfr[tap][ntl] = *(const s16x8*)(wbase + (tap * 2 + cc) * 4096 + ntl * 1024);
    };

    // ---- prologue stage: both cc halves, once per block ----
    {
        const int scc  = (t >= 160) ? 1 : 0;
        const int su   = t - scc * 160;
        const int cp   = su & 15, srow = su >> 4;
        const int sy   = y0 + srow - 1;           // img row (halo)
        if (t < 320) {
            float va[2][18];
            if (sy < 0 || sy >= HW) {
                #pragma unroll
                for (int e = 0; e < 2; ++e)
                    #pragma unroll
                    for (int px = 0; px < 18; ++px) va[e][px] = 0.f;
            } else {
                #pragma unroll
                for (int e = 0; e < 2; ++e) {
                    const float* rp = img + ((size_t)(b * 64 + scc * 32 + cp * 2 + e) * HW + sy) * HW;
                    va[e][0] = (x0 > 0) ? rp[x0 - 1] : 0.f;
                    #pragma unroll
                    for (int i2 = 0; i2 < 4; ++i2) {
                        const float4 v = *(const float4*)(rp + x0 + i2 * 4);
                        va[e][1 + 4 * i2] = v.x;
                        va[e][2 + 4 * i2] = v.y;
                        va[e][3 + 4 * i2] = v.z;
                        va[e][4 + 4 * i2] = v.w;
                    }
                    va[e][17] = (x0 + 16 < HW) ? rp[x0 + 16] : 0.f;
                }
            }
            char* wp = tile[scc] + srow * LP_ROW + (cp & 3) * 4;
            #pragma unroll
            for (int px = 0; px < 18; ++px) {
                char* a0 = wp + px * 64 + (((cp >> 2) ^ SWZ(px)) << 4);
                const float l1 = va[0][px], h1 = va[1][px];
                const float l2 = l1 * l1,   h2 = h1 * h1;
                const float l3 = l2 * l1,   h3 = h2 * h1;
                *(unsigned*)(a0)                = pack2(l1, h1);
                *(unsigned*)(a0 + LP_PHASE)     = pack2(l2, h2);
                *(unsigned*)(a0 + 2 * LP_PHASE) = pack2(l3, h3);
            }
        }
    }
    loadW(0);                          // after pack: va/bfr liveness disjoint
    __syncthreads();                   // both buffers ready

    auto compute_plane = [&](const char* bufbase, int p) {   // p compile-time at call sites
        const char* base = bufbase + p * LP_PHASE;
        #pragma unroll
        for (int kx = 0; kx < 3; ++kx) {
            const int pxr  = m + kx;
            const int c8sr = q ^ SWZ(pxr);
            const int abase = wvr * (2 * LP_ROW) + pxr * 64 + c8sr * 16;
            s16x8 af[4];
            #pragma unroll
            for (int r4 = 0; r4 < 4; ++r4)
                af[r4] = *(const s16x8*)&base[abase + r4 * LP_ROW];
            __builtin_amdgcn_s_setprio(1);
            #pragma unroll
            for (int ky = 0; ky < 3; ++ky)
                #pragma unroll
                for (int at = 0; at < 2; ++at)
                    #pragma unroll
                    for (int ntl = 0; ntl < 2; ++ntl)
                        acc[p][at][ntl] = __builtin_amdgcn_mfma_f32_16x16x32_bf16(
                            af[at + ky], bfr[ky * 3 + kx][ntl], acc[p][at][ntl], 0, 0, 0);
            __builtin_amdgcn_s_setprio(0);
        }
    };

    compute_plane(tile[0], 0);
    compute_plane(tile[0], 1);
    compute_plane(tile[0], 2);
    loadW(1);                          // register dep orders this after cc0 MFMAs
    compute_plane(tile[1], 0);
    compute_plane(tile[1], 1);
    compute_plane(tile[1], 2);

    // ---- epilogue: telescoped diffs, f32x2 packed; D: n = lane&15, px = q*4+reg ----
    #pragma unroll
    for (int ntl = 0; ntl < 2; ++ntl) {
        const int o = (oc2 * 2 + ntl) * 16 + (lane & 15);
        const float Sv = S[o];
        const float fS = -0.000287f / 75.f * Sv;
        const float cg1 = 0.8448f  + 0.001309f * Sv;
        const float D1  = 0.52992f - 0.003809f * Sv;
        const float D2  = 0.45312f + 0.001546f * Sv;
        const float D3  = 1.152f   - 0.006386f * Sv;
        const float D4  = 0.91392f - 0.00283f  * Sv;
        #pragma unroll
        for (int at = 0; at < 2; ++at) {
            float res[4];
            #pragma unroll
            for (int h = 0; h < 2; ++h) {
                const f32x2 u1 = {acc[0][at][ntl][2 * h], acc[0][at][ntl][2 * h + 1]};
                const f32x2 u2 = {acc[1][at][ntl][2 * h], acc[1][at][ntl][2 * h + 1]};
                const f32x2 u3 = {acc[2][at][ntl][2 * h], acc[2][at][ntl][2 * h + 1]};
                const f32x2 f  = fS   + 0.00354667f * u1 - 0.00146267f * u2;
                const f32x2 g1 = cg1  + 0.00619f    * u1 - 0.009f      * u2 + 0.001383f * u3;
                const f32x2 d1 = D1   - 0.00316f    * u1 + 0.00416f    * u2 + 0.016117f * u3;
                const f32x2 d2 = D2   - 0.00116f    * u1 + 0.006717f   * u2 - 0.00248f  * u3;
                const f32x2 d3 = D3   - 0.000753f   * u1 + 0.005643f   * u2 - 0.00602f  * u3;
                const f32x2 d4 = D4   - 0.000691f   * u1 + 0.00085f    * u2 - 0.00487f  * u3;
                f32x2 E;
                E.x = __expf(-10.f * f.x);
                E.y = __expf(-10.f * f.y);
                const f32x2 den1 = 1.f + E * 4.4816890703f;
                const f32x2 den2 = 1.f + E * 9.9741824548f;
                const f32x2 den3 = 1.f + E * 24.5325301971f;
                const f32x2 den4 = 1.f + E * 49.4024491055f;
                f32x2 o2 = g1;
                o2.x += __builtin_amdgcn_rcpf(den1.x) * d1.x + __builtin_amdgcn_rcpf(den2.x) * d2.x
                      + __builtin_amdgcn_rcpf(den3.x) * d3.x + __builtin_amdgcn_rcpf(den4.x) * d4.x;
                o2.y += __builtin_amdgcn_rcpf(den1.y) * d1.y + __builtin_amdgcn_rcpf(den2.y) * d2.y
                      + __builtin_amdgcn_rcpf(den3.y) * d3.y + __builtin_amdgcn_rcpf(den4.y) * d4.y;
                res[2 * h] = o2.x; res[2 * h + 1] = o2.y;
            }
            const int y = y0 + 2 * wvr + at;
            float* op = out + (((size_t)(b * 64 + o)) * HW + y) * HW + x0 + q * 4;
            *(float4*)op = make_float4(res[0], res[1], res[2], res[3]);
        }
    }
}

extern "C" void kernel_launch(void* const* d_in, const int* in_sizes, int n_in,
                              void* d_out, int out_size, void* d_ws, size_t ws_size,
                              hipStream_t stream) {
    const float* img = (const float*)d_in[0];
    const float* w   = (const float*)d_in[1];
    float* outp = (float*)d_out;
    unsigned short* wb = (unsigned short*)d_ws;          // 36,864 shorts
    float* S = (float*)(wb + 36864);                     // 64 floats

    hipLaunchKernelGGL(prep_w,     dim3(145), dim3(256), 0, stream, w, wb, S);
    hipLaunchKernelGGL(conv_fused, dim3(784), dim3(512), 0, stream, img, wb, S, outp);
}